// Round 9
// baseline (556.877 us; speedup 1.0000x reference)
//
#include <hip/hip_runtime.h>

#define N_NODES 8000
#define E_EDGES 128000
#define NUM_BASES 50
#define R2 400
#define GRID 512
#define HB2 64                  // histogram/scatter blocks
#define EPB2 (E_EDGES / HB2)    // 2000 edges per hist block
#define RT 16                   // relation tile in relW build

static __device__ __forceinline__ float bf2f(unsigned short u) {
    return __uint_as_float(((unsigned int)u) << 16);
}
static __device__ __forceinline__ unsigned short f2bf(float f) {
    unsigned int u = __float_as_uint(f);
    u += 0x7fffu + ((u >> 16) & 1u);   // round-to-nearest-even
    return (unsigned short)(u >> 16);
}

// ---------------------------------------------------------------------------
// k_zero: zero the barrier counters (80 B) every call (replay-safe).
// ---------------------------------------------------------------------------
__global__ __launch_bounds__(64) void k_zero(int4* __restrict__ p, int n4) {
    const int i = threadIdx.x;
    if (i < n4) p[i] = make_int4(0, 0, 0, 0);
}

// ---------------------------------------------------------------------------
// device-scope spin barrier. All GRID blocks are co-resident by capacity:
// LDS 33.6KB -> 4 blocks/CU * 256 CU = 1024 slots >= 512 blocks, so the
// dispatcher places every block immediately (no ordering assumption).
// ---------------------------------------------------------------------------
static __device__ __forceinline__ void gbar(int* ctr, int idx) {
    __syncthreads();
    if (threadIdx.x == 0) {
        __threadfence();   // agent-scope release of prior global writes
        __hip_atomic_fetch_add(ctr + idx, 1, __ATOMIC_RELEASE,
                               __HIP_MEMORY_SCOPE_AGENT);
        while (__hip_atomic_load(ctr + idx, __ATOMIC_ACQUIRE,
                                 __HIP_MEMORY_SCOPE_AGENT) < GRID) {
            __builtin_amdgcn_s_sleep(8);
        }
        __threadfence();   // agent-scope acquire before subsequent reads
    }
    __syncthreads();
}

// ---------------------------------------------------------------------------
// k_mega: whole RGCN layer in one persistent kernel, 5 phases / 4 barriers.
// ---------------------------------------------------------------------------
__global__ __launch_bounds__(256, 1) void k_mega(
    const float* __restrict__ feat, const float* __restrict__ rel_emb,
    const float* __restrict__ weight, const float* __restrict__ w_comp,
    const float* __restrict__ slw, const float* __restrict__ Wr,
    const float* __restrict__ br, const int* __restrict__ src,
    const int* __restrict__ dst, const int* __restrict__ etype,
    unsigned short* __restrict__ relWh, unsigned short* __restrict__ msg,
    int2* __restrict__ sedge, int* __restrict__ off, int* __restrict__ doff,
    int* __restrict__ dtot, int* __restrict__ bcnt, int* __restrict__ bbase,
    int* __restrict__ dbcnt, int* __restrict__ dbase, int* __restrict__ ctr,
    int* __restrict__ gcur, float* __restrict__ out)
{
    __shared__ int lds[8400];                 // 33.6 KB
    const int blk = blockIdx.x;
    const int t = threadIdx.x;
    const int lane = t & 63;
    const int wv = t >> 6;

    // ======== P0: per-block histograms (blocks 0..63)  ||  relW (64..163) ===
    if (blk < HB2) {
        for (int i = t; i < 8400; i += 256) lds[i] = 0;
        __syncthreads();
        const int e0 = blk * EPB2;
        for (int e = e0 + t; e < e0 + EPB2; e += 256) {
            atomicAdd(&lds[dst[e]], 1);              // LDS atomics only
            atomicAdd(&lds[8000 + etype[e]], 1);
        }
        __syncthreads();
        for (int i = t; i < 400; i += 256) bcnt[blk * 400 + i] = lds[8000 + i];
        for (int i = t; i < 8000; i += 256) dbcnt[blk * 8000 + i] = lds[i];
    } else if (blk < HB2 + 100) {
        const int u = blk - HB2;
        const int rt = u >> 2;                   // [0,25)
        const int pb = u & 3;
        const int r0 = rt * RT;
        const int p = pb * 256 + t;              // float4 index [0,1024)
        const float4* w4 = (const float4*)weight;
        float4 acc[RT];
#pragma unroll
        for (int rr = 0; rr < RT; ++rr) acc[rr] = make_float4(0.f, 0.f, 0.f, 0.f);
        for (int b = 0; b < NUM_BASES; ++b) {
            const float4 w = w4[b * 1024 + p];
#pragma unroll
            for (int rr = 0; rr < RT; ++rr) {
                const float c = w_comp[(r0 + rr) * NUM_BASES + b];
                acc[rr].x = fmaf(c, w.x, acc[rr].x);
                acc[rr].y = fmaf(c, w.y, acc[rr].y);
                acc[rr].z = fmaf(c, w.z, acc[rr].z);
                acc[rr].w = fmaf(c, w.w, acc[rr].w);
            }
        }
        ushort4* outh = (ushort4*)relWh;
#pragma unroll
        for (int rr = 0; rr < RT; ++rr) {
            ushort4 v;
            v.x = f2bf(acc[rr].x); v.y = f2bf(acc[rr].y);
            v.z = f2bf(acc[rr].z); v.w = f2bf(acc[rr].w);
            outh[(r0 + rr) * 1024 + p] = v;
        }
    }
    gbar(ctr, 0);

    // ======== P1: dst scan + per-hist-block bases (0..249) || etype (250) ===
    if (blk < 250) {
        const int n0 = blk * 32;
        {   // partial sums: thread t -> node (t&31), hist-block slice (t>>5)*8
            const int nl = t & 31, part = t >> 5;
            int s = 0;
            const int pb0 = part * 8;
            for (int b = pb0; b < pb0 + 8; ++b) s += dbcnt[b * 8000 + n0 + nl];
            lds[nl * 8 + part] = s;
        }
        __syncthreads();
        int myTot = 0, myIncl = 0;
        if (t < 32) {
            for (int p = 0; p < 8; ++p) myTot += lds[t * 8 + p];
            int v = myTot;
#pragma unroll
            for (int d = 1; d < 32; d <<= 1) {       // inclusive scan, 32 lanes
                const int u2 = __shfl_up(v, d, 64);
                if (t >= d) v += u2;
            }
            myIncl = v;
            if (t == 31) lds[8392] = atomicAdd(gcur, v);  // block segment base
        }
        __syncthreads();
        const int base = lds[8392];
        if (t < 32) {
            const int dn = base + myIncl - myTot;
            doff[n0 + t] = dn;
            dtot[n0 + t] = myTot;
            lds[8300 + t] = dn;
        }
        __syncthreads();
        // dbase[b][n] = doff[n] + prefix_b(dbcnt[.][n]); lane = hist block b
        for (int nl = wv; nl < 32; nl += 4) {
            const int n = n0 + nl;
            const int orig = dbcnt[lane * 8000 + n];
            int v = orig;
#pragma unroll
            for (int d = 1; d < 64; d <<= 1) {
                const int u2 = __shfl_up(v, d, 64);
                if (lane >= d) v += u2;
            }
            dbase[lane * 8000 + n] = lds[8300 + nl] + v - orig;
        }
    } else if (blk == 250) {
        for (int r = t; r < 400; r += 256) {
            int s = 0;
            for (int b = 0; b < HB2; ++b) s += bcnt[b * 400 + r];
            lds[r] = s;
        }
        __syncthreads();
        if (t == 0) {
            int run = 0;
            for (int r = 0; r < 400; ++r) { lds[400 + r] = run; run += lds[r]; }
            off[0] = 0;
        }
        __syncthreads();
        for (int r = t; r < 400; r += 256) {
            int run = lds[400 + r];
            off[r + 1] = run + lds[r];
            for (int b = 0; b < HB2; ++b) {
                bbase[b * 400 + r] = run;
                run += bcnt[b * 400 + r];
            }
        }
    }
    gbar(ctr, 1);

    // ======== P2: scatter (blocks 0..63, LDS cursors, zero global atomics) ==
    if (blk < HB2) {
        for (int i = t; i < 8000; i += 256) lds[i] = dbase[blk * 8000 + i];
        for (int i = t; i < 400; i += 256) lds[8000 + i] = bbase[blk * 400 + i];
        __syncthreads();
        const int e0 = blk * EPB2;
        for (int e = e0 + t; e < e0 + EPB2; e += 256) {
            const int r = etype[e];
            const int d = dst[e];
            const int rpos = atomicAdd(&lds[8000 + r], 1);
            const int dpos = atomicAdd(&lds[d], 1);
            sedge[rpos] = make_int2(src[e], dpos);
        }
    }
    gbar(ctr, 2);

    // ======== P3: edge GEMV, 2048 waves, W[r] in VGPR, XCD-banded ==========
    {
        const int band = blk & 7;                      // XCD band
        const int wib = (blk >> 3) * 4 + wv;           // wave-in-band [0,256)
        for (int task = wib; task < 250; task += 256) {  // 50 rel x 5 chunks
            const int r = band * 50 + task / 5;
            const int chunk = task % 5;
            const int beg = off[r];
            const int cnt = off[r + 1] - beg;
            const int cb = beg + (cnt * chunk) / 5;
            const int ce = beg + (cnt * (chunk + 1)) / 5;
            const unsigned short* __restrict__ Wh = relWh + r * 4096;
            float w[64];
#pragma unroll
            for (int i = 0; i < 64; ++i) w[i] = bf2f(Wh[i * 64 + lane]);
            int idx = cb;
            for (; idx + 1 < ce; idx += 2) {
                const int2 eA = sedge[idx];
                const int2 eB = sedge[idx + 1];
                const int sA = __builtin_amdgcn_readfirstlane(eA.x);
                const int dA = __builtin_amdgcn_readfirstlane(eA.y);
                const int sB = __builtin_amdgcn_readfirstlane(eB.x);
                const int dB = __builtin_amdgcn_readfirstlane(eB.y);
                const float* __restrict__ fA = feat + sA * 64;  // s_load
                const float* __restrict__ fB = feat + sB * 64;
                float a0 = 0.f, a1 = 0.f, a2 = 0.f, a3 = 0.f;
                float b0 = 0.f, b1 = 0.f, b2 = 0.f, b3 = 0.f;
#pragma unroll
                for (int i = 0; i < 64; i += 4) {
                    a0 = fmaf(fA[i    ], w[i    ], a0);  b0 = fmaf(fB[i    ], w[i    ], b0);
                    a1 = fmaf(fA[i + 1], w[i + 1], a1);  b1 = fmaf(fB[i + 1], w[i + 1], b1);
                    a2 = fmaf(fA[i + 2], w[i + 2], a2);  b2 = fmaf(fB[i + 2], w[i + 2], b2);
                    a3 = fmaf(fA[i + 3], w[i + 3], a3);  b3 = fmaf(fB[i + 3], w[i + 3], b3);
                }
                msg[dA * 64 + lane] = f2bf((a0 + a1) + (a2 + a3));
                msg[dB * 64 + lane] = f2bf((b0 + b1) + (b2 + b3));
            }
            if (idx < ce) {
                const int2 eA = sedge[idx];
                const int sA = __builtin_amdgcn_readfirstlane(eA.x);
                const int dA = __builtin_amdgcn_readfirstlane(eA.y);
                const float* __restrict__ frow = feat + sA * 64;
                float a0 = 0.f, a1 = 0.f, a2 = 0.f, a3 = 0.f;
#pragma unroll
                for (int i = 0; i < 64; i += 4) {
                    a0 = fmaf(frow[i    ], w[i    ], a0);
                    a1 = fmaf(frow[i + 1], w[i + 1], a1);
                    a2 = fmaf(frow[i + 2], w[i + 2], a2);
                    a3 = fmaf(frow[i + 3], w[i + 3], a3);
                }
                msg[dA * 64 + lane] = f2bf((a0 + a1) + (a2 + a3));
            }
        }
    }
    gbar(ctr, 3);

    // ======== P4: node epilogue (0..499) || rel_emb GEMM (500..511) =========
    float* ldsf = (float*)lds;
    if (blk < 500) {
        for (int i = t; i < 4096; i += 256) ldsf[i] = slw[i];
        __syncthreads();
#pragma unroll
        for (int q = 0; q < 4; ++q) {
            const int n = blk * 16 + wv * 4 + q;
            const int b0 = doff[n];
            const int b1 = b0 + dtot[n];
            const float* __restrict__ frow = feat + n * 64;   // uniform
            const float fa = frow[lane];
            float acc = 0.f;
#pragma unroll
            for (int i = 0; i < 64; ++i)
                acc = fmaf(frow[i], ldsf[i * 64 + lane], acc);
            float sm = 0.f;
            int jj = b0;
            for (; jj + 3 < b1; jj += 4) {
                const float m0 = bf2f(msg[jj * 64 + lane]);
                const float m1 = bf2f(msg[(jj + 1) * 64 + lane]);
                const float m2 = bf2f(msg[(jj + 2) * 64 + lane]);
                const float m3 = bf2f(msg[(jj + 3) * 64 + lane]);
                sm += (m0 + m1) + (m2 + m3);
            }
            for (; jj < b1; ++jj) sm += bf2f(msg[jj * 64 + lane]);
            const float inv = 1.0f / fmaxf((float)(b1 - b0), 1.0f);
            out[n * 128 + lane] = fa;
            out[n * 128 + 64 + lane] = fmaf(sm, inv, acc);
        }
    } else {
        for (int i = t; i < 4096; i += 256)
            ldsf[(i & 63) * 64 + (i >> 6)] = Wr[i];   // transposed
        __syncthreads();
        const int r0b = (blk - 500) * 34;
        const int r1b = (r0b + 34 < 400) ? (r0b + 34) : 400;
        for (int r = r0b + wv; r < r1b; r += 4) {
            const float* __restrict__ rrow = rel_emb + r * 64;  // uniform
            float acc = br[lane];
#pragma unroll
            for (int k = 0; k < 64; ++k)
                acc = fmaf(rrow[k], ldsf[k * 64 + lane], acc);
            out[N_NODES * 128 + r * 64 + lane] = acc;
        }
    }
}

// ---------------------------------------------------------------------------
extern "C" void kernel_launch(void* const* d_in, const int* in_sizes, int n_in,
                              void* d_out, int out_size, void* d_ws, size_t ws_size,
                              hipStream_t stream) {
    const float* feat    = (const float*)d_in[0];   // [8000,64]
    const float* rel_emb = (const float*)d_in[1];   // [400,64]
    const float* weight  = (const float*)d_in[2];   // [50,64,64]
    const float* w_comp  = (const float*)d_in[3];   // [400,50]
    const float* slw     = (const float*)d_in[4];   // [64,64]
    const float* Wr      = (const float*)d_in[5];   // [64,64]
    const float* br      = (const float*)d_in[6];   // [64]
    const int*   src     = (const int*)d_in[7];     // [128000]
    const int*   dst     = (const int*)d_in[8];     // [128000]
    const int*   etype   = (const int*)d_in[9];     // [128000]
    float* out = (float*)d_out;
    char* ws = (char*)d_ws;                          // 256 MiB (observed)

    unsigned short* relWh = (unsigned short*)(ws);            //  3,276,800
    unsigned short* msg   = (unsigned short*)(ws + 3276800);  // 16,384,000
    int2* sedge  = (int2*)(ws + 19660800);                    //  1,024,000
    int* off     = (int*)(ws + 20684800);                     //      1,664
    int* doff    = (int*)(ws + 20686464);                     //     32,000
    int* dtot    = (int*)(ws + 20718464);                     //     32,000
    int* bcnt    = (int*)(ws + 20750464);                     //    102,400
    int* bbase   = (int*)(ws + 20852864);                     //    102,400
    int* dbcnt   = (int*)(ws + 20955264);                     //  2,048,000
    int* dbase   = (int*)(ws + 23003264);                     //  2,048,000
    int* ctr     = (int*)(ws + 25051264);                     //         64
    int* gcur    = (int*)(ws + 25051328);                     //          4

    // zero barrier counters + global cursor (80 B) every call
    k_zero<<<1, 64, 0, stream>>>((int4*)ctr, 5);
    k_mega<<<GRID, 256, 0, stream>>>(feat, rel_emb, weight, w_comp, slw, Wr, br,
                                     src, dst, etype, relWh, msg, sedge, off,
                                     doff, dtot, bcnt, bbase, dbcnt, dbase,
                                     ctr, gcur, out);
}

// Round 10
// 544.088 us; speedup vs baseline: 1.0235x; 1.0235x over previous
//
#include <hip/hip_runtime.h>

#define N_NODES 8000
#define E_EDGES 128000
#define NUM_BASES 50
#define R2 400
#define GRID 512
#define HB2 64                  // histogram/scatter blocks
#define EPB2 (E_EDGES / HB2)    // 2000 edges per hist block
#define RT 16                   // relation tile in relW build

static __device__ __forceinline__ float bf2f(unsigned short u) {
    return __uint_as_float(((unsigned int)u) << 16);
}
static __device__ __forceinline__ unsigned short f2bf(float f) {
    unsigned int u = __float_as_uint(f);
    u += 0x7fffu + ((u >> 16) & 1u);   // round-to-nearest-even
    return (unsigned short)(u >> 16);
}

// ---------------------------------------------------------------------------
// k_zero: zero the barrier region (16 KB + gcur) every call (replay-safe).
// ---------------------------------------------------------------------------
__global__ __launch_bounds__(256) void k_zero(int4* __restrict__ p, int n4) {
    const int i = blockIdx.x * 256 + threadIdx.x;
    if (i < n4) p[i] = make_int4(0, 0, 0, 0);
}

// ---------------------------------------------------------------------------
// Two-level device barrier. R9's single-line spin (512 pollers, 0.2us period)
// saturated the memory-side coherence point (~130us/barrier). Here:
//   level 0: 8 group arrival counters (64 blocks each), 128B apart
//   level 1: root counter (8 adds); last group leader sets 8 release flags
//   wait:    spin on the GROUP FLAG only (64 pollers/line, s_sleep(64)~1.7us)
// Per-barrier-idx state (1024 ints): garr[8*32], root@256, flag[8]@(288+g*32).
// ---------------------------------------------------------------------------
static __device__ __forceinline__ void gbar(int* bar, int idx) {
    __syncthreads();
    if (threadIdx.x == 0) {
        const int g = blockIdx.x >> 6;            // 8 groups of 64 blocks
        int* base  = bar + idx * 1024;
        int* garr  = base + g * 32;
        int* root  = base + 8 * 32;
        int* gflag = base + (9 + g) * 32;
        __threadfence();                          // release prior global writes
        const int old = __hip_atomic_fetch_add(garr, 1, __ATOMIC_ACQ_REL,
                                               __HIP_MEMORY_SCOPE_AGENT);
        bool last_of_all = false;
        if (old == 63) {                          // group leader
            const int r = __hip_atomic_fetch_add(root, 1, __ATOMIC_ACQ_REL,
                                                 __HIP_MEMORY_SCOPE_AGENT);
            if (r == 7) {                         // last leader: release all
                last_of_all = true;
                for (int i = 0; i < 8; ++i)
                    __hip_atomic_store(base + (9 + i) * 32, 1, __ATOMIC_RELEASE,
                                       __HIP_MEMORY_SCOPE_AGENT);
            }
        }
        if (!last_of_all) {
            while (__hip_atomic_load(gflag, __ATOMIC_ACQUIRE,
                                     __HIP_MEMORY_SCOPE_AGENT) == 0) {
                __builtin_amdgcn_s_sleep(64);     // ~1.7us poll period
            }
        }
        __threadfence();                          // acquire side
    }
    __syncthreads();
}

// ---------------------------------------------------------------------------
// k_mega: whole RGCN layer in one persistent kernel, 5 phases / 4 barriers.
// (phase bodies identical to R9 -- only the barrier changed)
// ---------------------------------------------------------------------------
__global__ __launch_bounds__(256, 1) void k_mega(
    const float* __restrict__ feat, const float* __restrict__ rel_emb,
    const float* __restrict__ weight, const float* __restrict__ w_comp,
    const float* __restrict__ slw, const float* __restrict__ Wr,
    const float* __restrict__ br, const int* __restrict__ src,
    const int* __restrict__ dst, const int* __restrict__ etype,
    unsigned short* __restrict__ relWh, unsigned short* __restrict__ msg,
    int2* __restrict__ sedge, int* __restrict__ off, int* __restrict__ doff,
    int* __restrict__ dtot, int* __restrict__ bcnt, int* __restrict__ bbase,
    int* __restrict__ dbcnt, int* __restrict__ dbase, int* __restrict__ bar,
    int* __restrict__ gcur, float* __restrict__ out)
{
    __shared__ int lds[8400];                 // 33.6 KB
    const int blk = blockIdx.x;
    const int t = threadIdx.x;
    const int lane = t & 63;
    const int wv = t >> 6;

    // ======== P0: per-block histograms (blocks 0..63)  ||  relW (64..163) ===
    if (blk < HB2) {
        for (int i = t; i < 8400; i += 256) lds[i] = 0;
        __syncthreads();
        const int e0 = blk * EPB2;
        for (int e = e0 + t; e < e0 + EPB2; e += 256) {
            atomicAdd(&lds[dst[e]], 1);              // LDS atomics only
            atomicAdd(&lds[8000 + etype[e]], 1);
        }
        __syncthreads();
        for (int i = t; i < 400; i += 256) bcnt[blk * 400 + i] = lds[8000 + i];
        for (int i = t; i < 8000; i += 256) dbcnt[blk * 8000 + i] = lds[i];
    } else if (blk < HB2 + 100) {
        const int u = blk - HB2;
        const int rt = u >> 2;                   // [0,25)
        const int pb = u & 3;
        const int r0 = rt * RT;
        const int p = pb * 256 + t;              // float4 index [0,1024)
        const float4* w4 = (const float4*)weight;
        float4 acc[RT];
#pragma unroll
        for (int rr = 0; rr < RT; ++rr) acc[rr] = make_float4(0.f, 0.f, 0.f, 0.f);
        for (int b = 0; b < NUM_BASES; ++b) {
            const float4 w = w4[b * 1024 + p];
#pragma unroll
            for (int rr = 0; rr < RT; ++rr) {
                const float c = w_comp[(r0 + rr) * NUM_BASES + b];
                acc[rr].x = fmaf(c, w.x, acc[rr].x);
                acc[rr].y = fmaf(c, w.y, acc[rr].y);
                acc[rr].z = fmaf(c, w.z, acc[rr].z);
                acc[rr].w = fmaf(c, w.w, acc[rr].w);
            }
        }
        ushort4* outh = (ushort4*)relWh;
#pragma unroll
        for (int rr = 0; rr < RT; ++rr) {
            ushort4 v;
            v.x = f2bf(acc[rr].x); v.y = f2bf(acc[rr].y);
            v.z = f2bf(acc[rr].z); v.w = f2bf(acc[rr].w);
            outh[(r0 + rr) * 1024 + p] = v;
        }
    }
    gbar(bar, 0);

    // ======== P1: dst scan + per-hist-block bases (0..249) || etype (250) ===
    if (blk < 250) {
        const int n0 = blk * 32;
        {   // partial sums: thread t -> node (t&31), hist-block slice (t>>5)*8
            const int nl = t & 31, part = t >> 5;
            int s = 0;
            const int pb0 = part * 8;
            for (int b = pb0; b < pb0 + 8; ++b) s += dbcnt[b * 8000 + n0 + nl];
            lds[nl * 8 + part] = s;
        }
        __syncthreads();
        int myTot = 0, myIncl = 0;
        if (t < 32) {
            for (int p = 0; p < 8; ++p) myTot += lds[t * 8 + p];
            int v = myTot;
#pragma unroll
            for (int d = 1; d < 32; d <<= 1) {       // inclusive scan, 32 lanes
                const int u2 = __shfl_up(v, d, 64);
                if (t >= d) v += u2;
            }
            myIncl = v;
            if (t == 31) lds[8392] = atomicAdd(gcur, v);  // block segment base
        }
        __syncthreads();
        const int base = lds[8392];
        if (t < 32) {
            const int dn = base + myIncl - myTot;
            doff[n0 + t] = dn;
            dtot[n0 + t] = myTot;
            lds[8300 + t] = dn;
        }
        __syncthreads();
        // dbase[b][n] = doff[n] + prefix_b(dbcnt[.][n]); lane = hist block b
        for (int nl = wv; nl < 32; nl += 4) {
            const int n = n0 + nl;
            const int orig = dbcnt[lane * 8000 + n];
            int v = orig;
#pragma unroll
            for (int d = 1; d < 64; d <<= 1) {
                const int u2 = __shfl_up(v, d, 64);
                if (lane >= d) v += u2;
            }
            dbase[lane * 8000 + n] = lds[8300 + nl] + v - orig;
        }
    } else if (blk == 250) {
        for (int r = t; r < 400; r += 256) {
            int s = 0;
            for (int b = 0; b < HB2; ++b) s += bcnt[b * 400 + r];
            lds[r] = s;
        }
        __syncthreads();
        if (t == 0) {
            int run = 0;
            for (int r = 0; r < 400; ++r) { lds[400 + r] = run; run += lds[r]; }
            off[0] = 0;
        }
        __syncthreads();
        for (int r = t; r < 400; r += 256) {
            int run = lds[400 + r];
            off[r + 1] = run + lds[r];
            for (int b = 0; b < HB2; ++b) {
                bbase[b * 400 + r] = run;
                run += bcnt[b * 400 + r];
            }
        }
    }
    gbar(bar, 1);

    // ======== P2: scatter (blocks 0..63, LDS cursors, zero global atomics) ==
    if (blk < HB2) {
        for (int i = t; i < 8000; i += 256) lds[i] = dbase[blk * 8000 + i];
        for (int i = t; i < 400; i += 256) lds[8000 + i] = bbase[blk * 400 + i];
        __syncthreads();
        const int e0 = blk * EPB2;
        for (int e = e0 + t; e < e0 + EPB2; e += 256) {
            const int r = etype[e];
            const int d = dst[e];
            const int rpos = atomicAdd(&lds[8000 + r], 1);
            const int dpos = atomicAdd(&lds[d], 1);
            sedge[rpos] = make_int2(src[e], dpos);
        }
    }
    gbar(bar, 2);

    // ======== P3: edge GEMV, 2048 waves, W[r] in VGPR, XCD-banded ==========
    {
        const int band = blk & 7;                      // XCD band
        const int wib = (blk >> 3) * 4 + wv;           // wave-in-band [0,256)
        for (int task = wib; task < 250; task += 256) {  // 50 rel x 5 chunks
            const int r = band * 50 + task / 5;
            const int chunk = task % 5;
            const int beg = off[r];
            const int cnt = off[r + 1] - beg;
            const int cb = beg + (cnt * chunk) / 5;
            const int ce = beg + (cnt * (chunk + 1)) / 5;
            const unsigned short* __restrict__ Wh = relWh + r * 4096;
            float w[64];
#pragma unroll
            for (int i = 0; i < 64; ++i) w[i] = bf2f(Wh[i * 64 + lane]);
            int idx = cb;
            for (; idx + 1 < ce; idx += 2) {
                const int2 eA = sedge[idx];
                const int2 eB = sedge[idx + 1];
                const int sA = __builtin_amdgcn_readfirstlane(eA.x);
                const int dA = __builtin_amdgcn_readfirstlane(eA.y);
                const int sB = __builtin_amdgcn_readfirstlane(eB.x);
                const int dB = __builtin_amdgcn_readfirstlane(eB.y);
                const float* __restrict__ fA = feat + sA * 64;  // s_load
                const float* __restrict__ fB = feat + sB * 64;
                float a0 = 0.f, a1 = 0.f, a2 = 0.f, a3 = 0.f;
                float b0 = 0.f, b1 = 0.f, b2 = 0.f, b3 = 0.f;
#pragma unroll
                for (int i = 0; i < 64; i += 4) {
                    a0 = fmaf(fA[i    ], w[i    ], a0);  b0 = fmaf(fB[i    ], w[i    ], b0);
                    a1 = fmaf(fA[i + 1], w[i + 1], a1);  b1 = fmaf(fB[i + 1], w[i + 1], b1);
                    a2 = fmaf(fA[i + 2], w[i + 2], a2);  b2 = fmaf(fB[i + 2], w[i + 2], b2);
                    a3 = fmaf(fA[i + 3], w[i + 3], a3);  b3 = fmaf(fB[i + 3], w[i + 3], b3);
                }
                msg[dA * 64 + lane] = f2bf((a0 + a1) + (a2 + a3));
                msg[dB * 64 + lane] = f2bf((b0 + b1) + (b2 + b3));
            }
            if (idx < ce) {
                const int2 eA = sedge[idx];
                const int sA = __builtin_amdgcn_readfirstlane(eA.x);
                const int dA = __builtin_amdgcn_readfirstlane(eA.y);
                const float* __restrict__ frow = feat + sA * 64;
                float a0 = 0.f, a1 = 0.f, a2 = 0.f, a3 = 0.f;
#pragma unroll
                for (int i = 0; i < 64; i += 4) {
                    a0 = fmaf(frow[i    ], w[i    ], a0);
                    a1 = fmaf(frow[i + 1], w[i + 1], a1);
                    a2 = fmaf(frow[i + 2], w[i + 2], a2);
                    a3 = fmaf(frow[i + 3], w[i + 3], a3);
                }
                msg[dA * 64 + lane] = f2bf((a0 + a1) + (a2 + a3));
            }
        }
    }
    gbar(bar, 3);

    // ======== P4: node epilogue (0..499) || rel_emb GEMM (500..511) =========
    float* ldsf = (float*)lds;
    if (blk < 500) {
        for (int i = t; i < 4096; i += 256) ldsf[i] = slw[i];
        __syncthreads();
#pragma unroll
        for (int q = 0; q < 4; ++q) {
            const int n = blk * 16 + wv * 4 + q;
            const int b0 = doff[n];
            const int b1 = b0 + dtot[n];
            const float* __restrict__ frow = feat + n * 64;   // uniform
            const float fa = frow[lane];
            float acc = 0.f;
#pragma unroll
            for (int i = 0; i < 64; ++i)
                acc = fmaf(frow[i], ldsf[i * 64 + lane], acc);
            float sm = 0.f;
            int jj = b0;
            for (; jj + 3 < b1; jj += 4) {
                const float m0 = bf2f(msg[jj * 64 + lane]);
                const float m1 = bf2f(msg[(jj + 1) * 64 + lane]);
                const float m2 = bf2f(msg[(jj + 2) * 64 + lane]);
                const float m3 = bf2f(msg[(jj + 3) * 64 + lane]);
                sm += (m0 + m1) + (m2 + m3);
            }
            for (; jj < b1; ++jj) sm += bf2f(msg[jj * 64 + lane]);
            const float inv = 1.0f / fmaxf((float)(b1 - b0), 1.0f);
            out[n * 128 + lane] = fa;
            out[n * 128 + 64 + lane] = fmaf(sm, inv, acc);
        }
    } else {
        for (int i = t; i < 4096; i += 256)
            ldsf[(i & 63) * 64 + (i >> 6)] = Wr[i];   // transposed
        __syncthreads();
        const int r0b = (blk - 500) * 34;
        const int r1b = (r0b + 34 < 400) ? (r0b + 34) : 400;
        for (int r = r0b + wv; r < r1b; r += 4) {
            const float* __restrict__ rrow = rel_emb + r * 64;  // uniform
            float acc = br[lane];
#pragma unroll
            for (int k = 0; k < 64; ++k)
                acc = fmaf(rrow[k], ldsf[k * 64 + lane], acc);
            out[N_NODES * 128 + r * 64 + lane] = acc;
        }
    }
}

// ---------------------------------------------------------------------------
extern "C" void kernel_launch(void* const* d_in, const int* in_sizes, int n_in,
                              void* d_out, int out_size, void* d_ws, size_t ws_size,
                              hipStream_t stream) {
    const float* feat    = (const float*)d_in[0];   // [8000,64]
    const float* rel_emb = (const float*)d_in[1];   // [400,64]
    const float* weight  = (const float*)d_in[2];   // [50,64,64]
    const float* w_comp  = (const float*)d_in[3];   // [400,50]
    const float* slw     = (const float*)d_in[4];   // [64,64]
    const float* Wr      = (const float*)d_in[5];   // [64,64]
    const float* br      = (const float*)d_in[6];   // [64]
    const int*   src     = (const int*)d_in[7];     // [128000]
    const int*   dst     = (const int*)d_in[8];     // [128000]
    const int*   etype   = (const int*)d_in[9];     // [128000]
    float* out = (float*)d_out;
    char* ws = (char*)d_ws;                          // 256 MiB (observed)

    unsigned short* relWh = (unsigned short*)(ws);            //  3,276,800
    unsigned short* msg   = (unsigned short*)(ws + 3276800);  // 16,384,000
    int2* sedge  = (int2*)(ws + 19660800);                    //  1,024,000
    int* off     = (int*)(ws + 20684800);                     //      1,664
    int* doff    = (int*)(ws + 20686464);                     //     32,000
    int* dtot    = (int*)(ws + 20718464);                     //     32,000
    int* bcnt    = (int*)(ws + 20750464);                     //    102,400
    int* bbase   = (int*)(ws + 20852864);                     //    102,400
    int* dbcnt   = (int*)(ws + 20955264);                     //  2,048,000
    int* dbase   = (int*)(ws + 23003264);                     //  2,048,000
    int* bar     = (int*)(ws + 25051264);                     //     16,384
    int* gcur    = (int*)(ws + 25067648);                     //          4

    // zero barrier region (16,384 B) + gcur (4 B) -> 1028 int4
    k_zero<<<5, 256, 0, stream>>>((int4*)bar, 1028);
    k_mega<<<GRID, 256, 0, stream>>>(feat, rel_emb, weight, w_comp, slw, Wr, br,
                                     src, dst, etype, relWh, msg, sedge, off,
                                     doff, dtot, bcnt, bbase, dbcnt, dbase,
                                     bar, gcur, out);
}

// Round 11
// 110.158 us; speedup vs baseline: 5.0553x; 4.9392x over previous
//
#include <hip/hip_runtime.h>

#define N_NODES 8000
#define E_EDGES 128000
#define NUM_BASES 50
#define R2 400
#define HB 64                   // histogram/scatter blocks
#define EPB (E_EDGES / HB)      // 2000 edges per hist block
#define RT 16                   // relation tile in relW build
#define CPR 8                   // chunks per relation in edge kernel

static __device__ __forceinline__ float bf2f(unsigned short u) {
    return __uint_as_float(((unsigned int)u) << 16);
}
static __device__ __forceinline__ unsigned short f2bf(float f) {
    unsigned int u = __float_as_uint(f);
    u += 0x7fffu + ((u >> 16) & 1u);   // round-to-nearest-even
    return (unsigned short)(u >> 16);
}

// ---------------------------------------------------------------------------
// k_pre: blocks [0,100)   -> rel_weight (bf16) = w_comp @ weight (tiled)
//        blocks [100,164) -> per-block LDS histograms of etype AND dst,
//                            plain-stored to bcnt/dbcnt (NO global atomics)
// block 0 also resets gcur (plain store; kernel boundary orders it vs k_scan).
// ---------------------------------------------------------------------------
__global__ __launch_bounds__(256) void k_pre(const float* __restrict__ w_comp,
                                             const float* __restrict__ weight,
                                             unsigned short* __restrict__ relWh,
                                             const int* __restrict__ dst,
                                             const int* __restrict__ etype,
                                             int* __restrict__ bcnt,
                                             int* __restrict__ dbcnt,
                                             int* __restrict__ gcur) {
    __shared__ int lcnt[8400];               // dst[8000] + etype[400]
    const int blk = blockIdx.x;
    const int t = threadIdx.x;
    if (blk < 100) {
        if (blk == 0 && t == 0) gcur[0] = 0;
        const int rt = blk >> 2;             // [0,25)
        const int pb = blk & 3;
        const int r0 = rt * RT;
        const int p = pb * 256 + t;          // float4 index [0,1024)
        const float4* w4 = (const float4*)weight;
        float4 acc[RT];
#pragma unroll
        for (int rr = 0; rr < RT; ++rr) acc[rr] = make_float4(0.f, 0.f, 0.f, 0.f);
        for (int b = 0; b < NUM_BASES; ++b) {
            const float4 w = w4[b * 1024 + p];
#pragma unroll
            for (int rr = 0; rr < RT; ++rr) {
                const float c = w_comp[(r0 + rr) * NUM_BASES + b];
                acc[rr].x = fmaf(c, w.x, acc[rr].x);
                acc[rr].y = fmaf(c, w.y, acc[rr].y);
                acc[rr].z = fmaf(c, w.z, acc[rr].z);
                acc[rr].w = fmaf(c, w.w, acc[rr].w);
            }
        }
        ushort4* outh = (ushort4*)relWh;
#pragma unroll
        for (int rr = 0; rr < RT; ++rr) {
            ushort4 v;
            v.x = f2bf(acc[rr].x); v.y = f2bf(acc[rr].y);
            v.z = f2bf(acc[rr].z); v.w = f2bf(acc[rr].w);
            outh[(r0 + rr) * 1024 + p] = v;
        }
    } else {
        const int h = blk - 100;             // [0,64)
        for (int i = t; i < 8400; i += 256) lcnt[i] = 0;
        __syncthreads();
        const int e0 = h * EPB;
        for (int e = e0 + t; e < e0 + EPB; e += 256) {
            atomicAdd(&lcnt[dst[e]], 1);             // LDS atomics only
            atomicAdd(&lcnt[8000 + etype[e]], 1);
        }
        __syncthreads();
        for (int i = t; i < 8000; i += 256) dbcnt[h * 8000 + i] = lcnt[i];
        for (int i = t; i < 400; i += 256) bcnt[h * 400 + i] = lcnt[8000 + i];
    }
}

// ---------------------------------------------------------------------------
// k_scan: blocks [0,250) -> dst side: group of 32 nodes; coalesced LDS tile of
//         dbcnt[64][32]; per-node totals; segment base via ONE atomicAdd(gcur)
//         per block; writes doff/dtot and per-hist-block dbase.
//         block 250 -> etype side: off[401] + per-hist-block bbase.
// ---------------------------------------------------------------------------
__global__ __launch_bounds__(256) void k_scan(const int* __restrict__ bcnt,
                                              const int* __restrict__ dbcnt,
                                              int* __restrict__ off,
                                              int* __restrict__ doff,
                                              int* __restrict__ dtot,
                                              int* __restrict__ bbase,
                                              int* __restrict__ dbase,
                                              int* __restrict__ gcur) {
    const int t = threadIdx.x;
    const int lane = t & 63;
    const int wv = t >> 6;
    if (blockIdx.x < 250) {
        __shared__ int T[64 * 32];           // T[hb*32+nl]
        __shared__ int sdoff[32];
        __shared__ int sbase;
        const int n0 = blockIdx.x * 32;
        // coalesced tile load: 8 rows per pass (each row = 32 consecutive ints)
#pragma unroll
        for (int pass = 0; pass < 8; ++pass) {
            const int row = pass * 8 + (t >> 5);
            const int col = t & 31;
            T[row * 32 + col] = dbcnt[row * 8000 + n0 + col];
        }
        __syncthreads();
        // per-node totals (lanes 0..31 of wave 0) + 64-lane inclusive scan
        int tot = 0;
        if (t < 32) {
            for (int hb = 0; hb < 64; ++hb) tot += T[hb * 32 + t];
        }
        int v = (t < 64) ? tot : 0;
        if (t < 64) {
#pragma unroll
            for (int d = 1; d < 64; d <<= 1) {
                const int u = __shfl_up(v, d, 64);
                if (lane >= d) v += u;
            }
        }
        if (t == 31) sbase = atomicAdd(gcur, v);   // group segment base
        __syncthreads();
        if (t < 32) {
            const int dn = sbase + v - tot;        // exclusive within group
            doff[n0 + t] = dn;
            dtot[n0 + t] = tot;
            sdoff[t] = dn;
        }
        __syncthreads();
        // dbase[hb][n] = doff[n] + prefix_hb ; lane = hb, 4 waves over nl
        for (int nl = wv; nl < 32; nl += 4) {
            const int orig = T[lane * 32 + nl];
            int s = orig;
#pragma unroll
            for (int d = 1; d < 64; d <<= 1) {
                const int u = __shfl_up(s, d, 64);
                if (lane >= d) s += u;
            }
            dbase[lane * 8000 + n0 + nl] = sdoff[nl] + s - orig;
        }
    } else {
        __shared__ int s[800];
        for (int r = t; r < 400; r += 256) {
            int sum = 0;
            for (int hb = 0; hb < HB; ++hb) sum += bcnt[hb * 400 + r];
            s[r] = sum;
        }
        __syncthreads();
        if (t == 0) {
            int run = 0;
            for (int r = 0; r < 400; ++r) { s[400 + r] = run; run += s[r]; }
            off[0] = 0;
        }
        __syncthreads();
        for (int r = t; r < 400; r += 256) {
            int run = s[400 + r];
            off[r + 1] = run + s[r];
            for (int hb = 0; hb < HB; ++hb) {
                bbase[hb * 400 + r] = run;
                run += bcnt[hb * 400 + r];
            }
        }
    }
}

// ---------------------------------------------------------------------------
// k_scatter: block h = hist block; LDS cursors seeded from dbase/bbase ->
// ZERO global atomics. sedge[rpos] = {src, dpos}; msg will land dst-sorted.
// ---------------------------------------------------------------------------
__global__ __launch_bounds__(256) void k_scatter(const int* __restrict__ src,
                                                 const int* __restrict__ dst,
                                                 const int* __restrict__ etype,
                                                 const int* __restrict__ bbase,
                                                 const int* __restrict__ dbase,
                                                 int2* __restrict__ sedge) {
    __shared__ int cur[8400];                // dst cursors[8000] + etype[400]
    const int h = blockIdx.x;                // [0,64)
    const int t = threadIdx.x;
    for (int i = t; i < 8000; i += 256) cur[i] = dbase[h * 8000 + i];
    for (int i = t; i < 400; i += 256) cur[8000 + i] = bbase[h * 400 + i];
    __syncthreads();
    const int e0 = h * EPB;
    for (int e = e0 + t; e < e0 + EPB; e += 256) {
        const int r = etype[e];
        const int d = dst[e];
        const int rpos = atomicAdd(&cur[8000 + r], 1);   // LDS atomic
        const int dpos = atomicAdd(&cur[d], 1);          // LDS atomic
        sedge[rpos] = make_int2(src[e], dpos);
    }
}

// ---------------------------------------------------------------------------
// k_edge: ONE WAVE per block, __launch_bounds__(64,1) -> W[r] column stays in
// VGPRs. XCD-banded relations; scalarized feat rows (s_load); ILP-2.
// ---------------------------------------------------------------------------
__global__ __launch_bounds__(64, 1) void k_edge(const float* __restrict__ feat,
                                                const unsigned short* __restrict__ relWh,
                                                const int2* __restrict__ sedge,
                                                const int* __restrict__ off,
                                                unsigned short* __restrict__ msg) {
    const int blk = blockIdx.x;              // [0, 3200)
    const int band = blk & 7;
    const int j = blk >> 3;                  // [0,400)
    const int r = band * 50 + (j >> 3);      // CPR=8
    const int chunk = j & 7;
    const int lane = threadIdx.x;
    const int beg = off[r];
    const int cnt = off[r + 1] - beg;
    const int cbeg = beg + (cnt * chunk) / CPR;
    const int cend = beg + (cnt * (chunk + 1)) / CPR;

    const unsigned short* __restrict__ Wh = relWh + r * 4096;
    float w[64];
#pragma unroll
    for (int i = 0; i < 64; ++i) w[i] = bf2f(Wh[i * 64 + lane]);

    int idx = cbeg;
    for (; idx + 1 < cend; idx += 2) {
        const int2 eA = sedge[idx];
        const int2 eB = sedge[idx + 1];
        const int sA = __builtin_amdgcn_readfirstlane(eA.x);
        const int dA = __builtin_amdgcn_readfirstlane(eA.y);
        const int sB = __builtin_amdgcn_readfirstlane(eB.x);
        const int dB = __builtin_amdgcn_readfirstlane(eB.y);
        const float* __restrict__ fA = feat + sA * 64;   // uniform -> s_load
        const float* __restrict__ fB = feat + sB * 64;
        float a0 = 0.f, a1 = 0.f, a2 = 0.f, a3 = 0.f;
        float b0 = 0.f, b1 = 0.f, b2 = 0.f, b3 = 0.f;
#pragma unroll
        for (int i = 0; i < 64; i += 4) {
            a0 = fmaf(fA[i    ], w[i    ], a0);  b0 = fmaf(fB[i    ], w[i    ], b0);
            a1 = fmaf(fA[i + 1], w[i + 1], a1);  b1 = fmaf(fB[i + 1], w[i + 1], b1);
            a2 = fmaf(fA[i + 2], w[i + 2], a2);  b2 = fmaf(fB[i + 2], w[i + 2], b2);
            a3 = fmaf(fA[i + 3], w[i + 3], a3);  b3 = fmaf(fB[i + 3], w[i + 3], b3);
        }
        msg[dA * 64 + lane] = f2bf((a0 + a1) + (a2 + a3));  // one 128B line
        msg[dB * 64 + lane] = f2bf((b0 + b1) + (b2 + b3));
    }
    if (idx < cend) {
        const int2 eA = sedge[idx];
        const int sA = __builtin_amdgcn_readfirstlane(eA.x);
        const int dA = __builtin_amdgcn_readfirstlane(eA.y);
        const float* __restrict__ frow = feat + sA * 64;
        float a0 = 0.f, a1 = 0.f, a2 = 0.f, a3 = 0.f;
#pragma unroll
        for (int i = 0; i < 64; i += 4) {
            a0 = fmaf(frow[i    ], w[i    ], a0);
            a1 = fmaf(frow[i + 1], w[i + 1], a1);
            a2 = fmaf(frow[i + 2], w[i + 2], a2);
            a3 = fmaf(frow[i + 3], w[i + 3], a3);
        }
        msg[dA * 64 + lane] = f2bf((a0 + a1) + (a2 + a3));
    }
}

// ---------------------------------------------------------------------------
// k_post: blocks [0,500)   -> node epilogue, contiguous mailbox sum (ILP-4),
//                             degree from dtot
//         blocks [500,600) -> rel_emb @ W_R^T + b
// ---------------------------------------------------------------------------
__global__ __launch_bounds__(256) void k_post(const float* __restrict__ feat,
                                              const float* __restrict__ slw,
                                              const int* __restrict__ doff,
                                              const int* __restrict__ dtot,
                                              const unsigned short* __restrict__ msg,
                                              const float* __restrict__ rel_emb,
                                              const float* __restrict__ Wr,
                                              const float* __restrict__ br,
                                              float* __restrict__ out) {
    __shared__ float s_w[4096];
    const int blk = blockIdx.x;
    const int t = threadIdx.x;
    const int lane = t & 63;
    const int wv = t >> 6;
    if (blk < 500) {
#pragma unroll
        for (int k = 0; k < 16; ++k) s_w[k * 256 + t] = slw[k * 256 + t];
        __syncthreads();
#pragma unroll
        for (int q = 0; q < 4; ++q) {
            const int n = blk * 16 + wv * 4 + q;
            const int b0 = doff[n];
            const int b1 = b0 + dtot[n];
            const float* __restrict__ frow = feat + n * 64;   // uniform
            const float fa = frow[lane];
            float acc = 0.f;
#pragma unroll
            for (int i = 0; i < 64; ++i)
                acc = fmaf(frow[i], s_w[i * 64 + lane], acc);  // 2-way alias: free
            float sm = 0.f;
            int jj = b0;
            for (; jj + 3 < b1; jj += 4) {                     // contiguous rows
                const float m0 = bf2f(msg[jj * 64 + lane]);
                const float m1 = bf2f(msg[(jj + 1) * 64 + lane]);
                const float m2 = bf2f(msg[(jj + 2) * 64 + lane]);
                const float m3 = bf2f(msg[(jj + 3) * 64 + lane]);
                sm += (m0 + m1) + (m2 + m3);
            }
            for (; jj < b1; ++jj) sm += bf2f(msg[jj * 64 + lane]);
            const float inv = 1.0f / fmaxf((float)(b1 - b0), 1.0f);
            out[n * 128 + lane] = fa;
            out[n * 128 + 64 + lane] = fmaf(sm, inv, acc);
        }
    } else {
        // s_w[k*64+j] = Wr[j*64+k]
#pragma unroll
        for (int k = 0; k < 16; ++k) {
            const int idx = k * 256 + t;
            s_w[(idx & 63) * 64 + (idx >> 6)] = Wr[idx];
        }
        __syncthreads();
        const int r = (blk - 500) * 4 + wv;
        const float* __restrict__ rrow = rel_emb + r * 64;     // uniform
        float acc = br[lane];
#pragma unroll
        for (int k = 0; k < 64; ++k)
            acc = fmaf(rrow[k], s_w[k * 64 + lane], acc);
        out[N_NODES * 128 + r * 64 + lane] = acc;
    }
}

// ---------------------------------------------------------------------------
extern "C" void kernel_launch(void* const* d_in, const int* in_sizes, int n_in,
                              void* d_out, int out_size, void* d_ws, size_t ws_size,
                              hipStream_t stream) {
    const float* feat    = (const float*)d_in[0];   // [8000,64]
    const float* rel_emb = (const float*)d_in[1];   // [400,64]
    const float* weight  = (const float*)d_in[2];   // [50,64,64]
    const float* w_comp  = (const float*)d_in[3];   // [400,50]
    const float* slw     = (const float*)d_in[4];   // [64,64]
    const float* Wr      = (const float*)d_in[5];   // [64,64]
    const float* br      = (const float*)d_in[6];   // [64]
    const int*   src     = (const int*)d_in[7];     // [128000]
    const int*   dst     = (const int*)d_in[8];     // [128000]
    const int*   etype   = (const int*)d_in[9];     // [128000]
    float* out = (float*)d_out;
    char* ws = (char*)d_ws;                          // 256 MiB available

    unsigned short* relWh = (unsigned short*)(ws);            //  3,276,800
    unsigned short* msg   = (unsigned short*)(ws + 3276800);  // 16,384,000
    int2* sedge  = (int2*)(ws + 19660800);                    //  1,024,000
    int* off     = (int*)(ws + 20684800);                     //      1,664
    int* doff    = (int*)(ws + 20686464);                     //     32,000
    int* dtot    = (int*)(ws + 20718464);                     //     32,000
    int* bcnt    = (int*)(ws + 20750464);                     //    102,400
    int* bbase   = (int*)(ws + 20852864);                     //    102,400
    int* dbcnt   = (int*)(ws + 20955264);                     //  2,048,000
    int* dbase   = (int*)(ws + 23003264);                     //  2,048,000
    int* gcur    = (int*)(ws + 25051264);                     //          4

    k_pre<<<164, 256, 0, stream>>>(w_comp, weight, relWh, dst, etype,
                                   bcnt, dbcnt, gcur);
    k_scan<<<251, 256, 0, stream>>>(bcnt, dbcnt, off, doff, dtot,
                                    bbase, dbase, gcur);
    k_scatter<<<HB, 256, 0, stream>>>(src, dst, etype, bbase, dbase, sedge);
    k_edge<<<R2 * CPR, 64, 0, stream>>>(feat, relWh, sedge, off, msg);
    k_post<<<600, 256, 0, stream>>>(feat, slw, doff, dtot, msg,
                                    rel_emb, Wr, br, out);
}